// Round 1
// baseline (201.660 us; speedup 1.0000x reference)
//
#include <hip/hip_runtime.h>
#include <stdint.h>
#include <stddef.h>

typedef __bf16 bf16;
typedef __bf16 bf16x8 __attribute__((ext_vector_type(8)));
typedef float f32x4 __attribute__((ext_vector_type(4)));

// ---------------------------------------------------------------------------
// async global->LDS, 16B per lane. LDS dest is wave-uniform base + lane*16.
// ---------------------------------------------------------------------------
__device__ __forceinline__ void global_to_lds16(const void* g, void* l) {
  const __attribute__((address_space(1))) unsigned* gp =
      reinterpret_cast<const __attribute__((address_space(1))) unsigned*>(
          reinterpret_cast<uintptr_t>(g));
  __attribute__((address_space(3))) unsigned* lp =
      reinterpret_cast<__attribute__((address_space(3))) unsigned*>(
          reinterpret_cast<uintptr_t>(l));
  __builtin_amdgcn_global_load_lds(gp, lp, 16, 0, 0);
}

// ---------------------------------------------------------------------------
// XCD-aware tile swizzle for 64-tile (8x8) GEMMs.
// ---------------------------------------------------------------------------
__device__ __forceinline__ void tile8x8_swizzle(int t, int& bx, int& by) {
  bx = (((t >> 3) & 1) << 2) | (t & 3);
  by = (((t >> 4) & 3) << 1) | ((t >> 2) & 1);
}

// ---------------------------------------------------------------------------
// 128x128-tile NT GEMM body, BK=64, PING-PONG double-buffered LDS (64 KB).
// One barrier per K-iteration:
//   issue tile0->buf0;  loop: { barrier; issue k+1 -> buf[p^1]; compute buf[p] }
// C = A * B^T. K=1024, lda=ldb=ldc=1024. K-order unchanged -> bit-identical.
// ---------------------------------------------------------------------------
template <typename OutT>
__device__ __forceinline__ void gemm128_body(const bf16* __restrict__ A,
                                             const bf16* __restrict__ B,
                                             OutT* __restrict__ C,
                                             int bx, int by) {
  __shared__ bf16 As[2][128 * 64];   // [buf][half*4096 + row*32 + col]
  __shared__ bf16 Bs[2][128 * 64];

  const int tid = threadIdx.x;
  const int wave = tid >> 6, lane = tid & 63;
  const int quad = lane >> 4, l16 = lane & 15;
  const int rowBase = by * 128;
  const int colBase = bx * 128;
  const int waveM = (wave >> 1) * 64, waveN = (wave & 1) * 64;

  // staging map: thread t covers global row t/4, cols (t&3)*8 .. +7
  const int sr = tid >> 2;
  const int sc = (tid & 3) * 8;
  const bf16* Ag0 = A + (size_t)(rowBase + sr) * 1024 + sc;   // rows 0..63
  const bf16* Ag1 = Ag0 + (size_t)64 * 1024;                  // rows 64..127
  const bf16* Bg0 = B + (size_t)(colBase + sr) * 1024 + sc;
  const bf16* Bg1 = Bg0 + (size_t)64 * 1024;

  const int woff = wave * 1024;  // byte offset of this wave's 16-row slab

  // issue the 8 async 16B/lane loads for K-tile starting at k0 into buffer p
  auto issue = [&](int k0, int p) {
    char* aB = (char*)As[p] + woff;
    char* bB = (char*)Bs[p] + woff;
    global_to_lds16(Ag0 + k0,      aB);             // half0 rows 0..63
    global_to_lds16(Ag1 + k0,      aB + 4096);      // half0 rows 64..127
    global_to_lds16(Ag0 + k0 + 32, aB + 8192);      // half1 rows 0..63
    global_to_lds16(Ag1 + k0 + 32, aB + 12288);     // half1 rows 64..127
    global_to_lds16(Bg0 + k0,      bB);
    global_to_lds16(Bg1 + k0,      bB + 4096);
    global_to_lds16(Bg0 + k0 + 32, bB + 8192);
    global_to_lds16(Bg1 + k0 + 32, bB + 12288);
  };

  f32x4 acc[4][4] = {};

  issue(0, 0);
  int p = 0;
#pragma unroll 1
  for (int k0 = 0; k0 < 1024; k0 += 64, p ^= 1) {
    __syncthreads();                 // drains loads for tile k0 (buf p)
    if (k0 + 64 < 1024) issue(k0 + 64, p ^ 1);   // prefetch into other buf
#pragma unroll
    for (int kk = 0; kk < 2; kk++) {
      const bf16* base = As[p] + kk * 4096;
      const bf16* baseB = Bs[p] + kk * 4096;
      bf16x8 af[4], bfr[4];
#pragma unroll
      for (int mi = 0; mi < 4; mi++)
        af[mi] = *(const bf16x8*)(base + (waveM + mi * 16 + l16) * 32 + quad * 8);
#pragma unroll
      for (int ni = 0; ni < 4; ni++)
        bfr[ni] = *(const bf16x8*)(baseB + (waveN + ni * 16 + l16) * 32 + quad * 8);
#pragma unroll
      for (int mi = 0; mi < 4; mi++)
#pragma unroll
        for (int ni = 0; ni < 4; ni++)
          acc[mi][ni] = __builtin_amdgcn_mfma_f32_16x16x32_bf16(af[mi], bfr[ni],
                                                                acc[mi][ni], 0, 0, 0);
    }
  }

  OutT* Cb = C + (size_t)(rowBase + waveM) * 1024 + colBase + waveN;
#pragma unroll
  for (int mi = 0; mi < 4; mi++)
#pragma unroll
    for (int ni = 0; ni < 4; ni++)
#pragma unroll
      for (int r = 0; r < 4; r++)
        Cb[(size_t)(mi * 16 + quad * 4 + r) * 1024 + ni * 16 + l16] =
            (OutT)acc[mi][ni][r];
}

// ---------------------------------------------------------------------------
// fused prep kernel. Flat grid of 5120 independent blocks:
//   [0,    2560)  : fp32->bf16 convert of 5 row-major Ws (512 blocks each)
//   [2560, 4096)  : fp32->bf16 transpose of 6 Ws (256 blocks each)
//   [4096, 5120)  : G build, one block per row j (LDS scatter via perm)
// ---------------------------------------------------------------------------
struct PrepArgs {
  const float* cvt_src[5]; bf16* cvt_dst[5];
  const float* tr_src[6];  bf16* tr_dst[6];
  const float* Wdec; const int* praw; bf16* Gbf;
};

__global__ __launch_bounds__(256) void prep_all(PrepArgs p) {
  __shared__ alignas(16) char smem[64 * 65 * 2];
  const int b = blockIdx.x;
  const int tid = threadIdx.x;

  if (b < 2560) {  // ---- convert row-major W ----
    const int m = b >> 9, blk = b & 511;
    const float* __restrict__ src = p.cvt_src[m];
    bf16* __restrict__ dst = p.cvt_dst[m];
    const int i = (blk * 256 + tid) * 8;
    float4 a = *(const float4*)(src + i);
    float4 c = *(const float4*)(src + i + 4);
    bf16x8 o;
    o[0] = (bf16)a.x; o[1] = (bf16)a.y; o[2] = (bf16)a.z; o[3] = (bf16)a.w;
    o[4] = (bf16)c.x; o[5] = (bf16)c.y; o[6] = (bf16)c.z; o[7] = (bf16)c.w;
    *(bf16x8*)(dst + i) = o;
  } else if (b < 4096) {  // ---- transpose+convert W ----
    const int t = b - 2560;
    const int m = t >> 8, r = t & 255;
    const float* __restrict__ src = p.tr_src[m];
    bf16* __restrict__ dst = p.tr_dst[m];
    bf16(*tile)[65] = reinterpret_cast<bf16(*)[65]>(smem);
    const int bx = (r & 15) * 64;
    const int by = (r >> 4) * 64;
    const int tx = tid & 63;
    const int ty4 = tid >> 6;
#pragma unroll
    for (int rr = 0; rr < 16; rr++) {
      int row = ty4 * 16 + rr;
      tile[row][tx] = (bf16)src[(size_t)(by + row) * 1024 + bx + tx];
    }
    __syncthreads();
#pragma unroll
    for (int rr = 0; rr < 16; rr++) {
      int row = ty4 * 16 + rr;
      dst[(size_t)(bx + row) * 1024 + by + tx] = tile[tx][row];
    }
  } else {  // ---- G build: G[j,d] = sum_{k: perm[k]==d} W_dec[j,k] ----
    const int j = b - 4096;
    float* row = (float*)smem;
    int* perm_l = (int*)(smem + 4096);
    int* nzp = (int*)(smem + 4096 + 1024);
#pragma unroll
    for (int c = 0; c < 4; c++) row[tid * 4 + c] = 0.f;
    if (tid == 0) *nzp = 0;
    __syncthreads();
    // int64 little-endian perm has all-zero high words.
    if (tid < 128 && p.praw[2 * tid + 1] != 0) atomicOr(nzp, 1);
    __syncthreads();
    const int is64 = (*nzp == 0);
    perm_l[tid] = is64 ? p.praw[2 * tid] : p.praw[tid];
    __syncthreads();
    atomicAdd(&row[perm_l[tid]], p.Wdec[(size_t)j * 256 + tid]);
    __syncthreads();
#pragma unroll
    for (int c = 0; c < 4; c++)
      p.Gbf[(size_t)j * 1024 + tid * 4 + c] = (bf16)row[tid * 4 + c];
  }
}

// ---------------------------------------------------------------------------
// Tree-level kernel: blocks [0, nG*64) do batched 128-tile NT GEMMs with
// XCD-aware tile swizzle; blocks >= nG*64 each convert EIGHT 2048-float
// x-units fp32->bf16 (fatter filler blocks: fewer dispatch churns, and the
// 8 iterations pipeline their loads).
// ---------------------------------------------------------------------------
struct TreeArgs {
  const bf16* A[6]; const bf16* B[6]; bf16* C[6];
  int nG;
  const float* x; bf16* xbf; int ubase;
};

__global__ __launch_bounds__(256) void tree_level(TreeArgs a) {
  const int b = blockIdx.x;
  const int gBlocks = a.nG * 64;
  if (b < gBlocks) {
    const int z = b >> 6, t = b & 63;
    int bx, by;
    tile8x8_swizzle(t, bx, by);
    gemm128_body<bf16>(a.A[z], a.B[z], a.C[z], bx, by);
  } else {
    const int u0 = a.ubase + (b - gBlocks) * 8;
#pragma unroll
    for (int u = 0; u < 8; u++) {
      const int i = (u0 + u) * 2048 + (int)threadIdx.x * 8;
      float4 v0 = *(const float4*)(a.x + i);
      float4 v1 = *(const float4*)(a.x + i + 4);
      bf16x8 o;
      o[0] = (bf16)v0.x; o[1] = (bf16)v0.y; o[2] = (bf16)v0.z; o[3] = (bf16)v0.w;
      o[4] = (bf16)v1.x; o[5] = (bf16)v1.y; o[6] = (bf16)v1.z; o[7] = (bf16)v1.w;
      *(bf16x8*)(a.xbf + i) = o;
    }
  }
}

// ---------------------------------------------------------------------------
// Step 4: R = NT(Q0, Q1t) (64 tiles, runs first) CONCURRENT WITH
// S = NT(xbf, Q2)  (8192x1024 out, 512 tiles, final_gemm-style XCD mapping).
// This is the reassociation out = x*F^T = (x*Q2^T)*R^T: the big S GEMM
// replaces the old serialized L4 level and soaks up the CUs that the
// 64-tile R GEMM leaves idle.
// ---------------------------------------------------------------------------
struct L3SArgs {
  const bf16* Q0; const bf16* Q1t; bf16* R;
  const bf16* xbf; const bf16* Q2; bf16* S;
};

__global__ __launch_bounds__(256) void l3s_level(L3SArgs a) {
  const int b = blockIdx.x;
  if (b < 64) {
    int bx, by;
    tile8x8_swizzle(b, bx, by);
    gemm128_body<bf16>(a.Q0, a.Q1t, a.R, bx, by);
  } else {
    const int t = b - 64;
    gemm128_body<bf16>(a.xbf, a.Q2, a.S, t >> 6, t & 63);
  }
}

// ---------------------------------------------------------------------------
// Final: out = S * R^T, fp32 out. M=8192, N=1024, K=1024. Flat 512-block
// grid with bx = b>>6, by = b&63: XCD k (b%8==k) owns 8 A-panels + 8
// B-panels = 4 MB working set (fits its private L2).
// ---------------------------------------------------------------------------
__global__ __launch_bounds__(256) void final_gemm(const bf16* __restrict__ A,
                                                  const bf16* __restrict__ B,
                                                  float* __restrict__ C) {
  const int b = blockIdx.x;
  gemm128_body<float>(A, B, C, b >> 6, b & 63);
}

// ---------------------------------------------------------------------------
// Host launcher.  5 kernels.
// out = x @ (G * W9 * W8 * W8 * W7 * W6 * W5 * W4 * W3 * W2 * W1 * W0)^T
// Tree: P0=G*W9  P1=(W8*W8)^T  P2=W7*W6  P3=(W5*W4)^T  P4=W3*W2  P5=(W1*W0)^T
//       Q0=NT(P0,P1) Q1t=NT(P3,P2) Q2=NT(P4,P5)=W3W2W1W0
//       step4: R=NT(Q0,Q1t)  ||  S=NT(xbf,Q2)=x*(W3W2W1W0)^T
//       out = NT(S, R).           (algebra: out = x*F^T = (x*Q2^T)*R^T)
// x convert spread across L1/L2 as filler (S consumes xbf at step 4).
// ---------------------------------------------------------------------------
extern "C" void kernel_launch(void* const* d_in, const int* in_sizes, int n_in,
                              void* d_out, int out_size, void* d_ws, size_t ws_size,
                              hipStream_t stream) {
  const float* x    = (const float*)d_in[0];
  const float* Wsrc = (const float*)d_in[1];   // 10 x 1024 x 1024
  const float* Wdec = (const float*)d_in[2];   // 1024 x 256
  const int*   praw = (const int*)d_in[3];
  float* out = (float*)d_out;

  constexpr size_t MAT  = 1024ull * 1024ull;
  constexpr size_t SLOT = 2ull * 1024 * 1024;  // 2 MiB = one bf16 DxD matrix

  char* ws = (char*)d_ws;
  bf16* Wrm[5];  // W1, W3, W5, W7, W8 (row-major bf16)
  for (int i = 0; i < 5; i++) Wrm[i] = (bf16*)(ws + (size_t)i * SLOT);
  bf16* Wt[6];   // W0^T, W2^T, W4^T, W6^T, W8^T, W9^T
  for (int i = 0; i < 6; i++) Wt[i] = (bf16*)(ws + (size_t)(5 + i) * SLOT);
  bf16* Gbf = (bf16*)(ws + 11 * SLOT);
  bf16* xbf = (bf16*)(ws + 12 * SLOT);         // 8 slots (16 MiB)
  bf16* P[6];
  for (int i = 0; i < 6; i++) P[i] = (bf16*)(ws + (size_t)(20 + i) * SLOT);
  bf16* Q[3];
  for (int i = 0; i < 3; i++) Q[i] = (bf16*)(ws + (size_t)(26 + i) * SLOT);
  bf16* Rb = (bf16*)(ws + 29 * SLOT);
  bf16* Sb = (bf16*)(ws + 31 * SLOT);          // 8 slots; total ws use: 78 MiB

  // 1) fused prep (W converts, W transposes, G)
  PrepArgs pa;
  const int rmIdx[5] = {1, 3, 5, 7, 8};
  for (int i = 0; i < 5; i++) { pa.cvt_src[i] = Wsrc + (size_t)rmIdx[i] * MAT; pa.cvt_dst[i] = Wrm[i]; }
  const int trIdx[6] = {0, 2, 4, 6, 8, 9};
  for (int i = 0; i < 6; i++) { pa.tr_src[i] = Wsrc + (size_t)trIdx[i] * MAT; pa.tr_dst[i] = Wt[i]; }
  pa.Wdec = Wdec; pa.praw = praw; pa.Gbf = Gbf;
  prep_all<<<dim3(5120), 256, 0, stream>>>(pa);

  // 2) L1: 6 GEMMs (384 blocks) + xcvt units [0,2048) as 256 8-unit blocks
  TreeArgs L1{};
  const bf16* l1a[6] = {Gbf, Wt[4], Wrm[3], Wt[2], Wrm[1], Wt[0]};
  const bf16* l1b[6] = {Wt[5], Wrm[4], Wt[3], Wrm[2], Wt[1], Wrm[0]};
  for (int i = 0; i < 6; i++) { L1.A[i] = l1a[i]; L1.B[i] = l1b[i]; L1.C[i] = P[i]; }
  L1.nG = 6; L1.x = x; L1.xbf = xbf; L1.ubase = 0;
  tree_level<<<dim3(384 + 256), 256, 0, stream>>>(L1);

  // 3) L2: Q0=NT(P0,P1) Q1t=NT(P3,P2) Q2=NT(P4,P5) + xcvt units [2048,4096)
  TreeArgs L2{};
  const bf16* l2a[3] = {P[0], P[3], P[4]};
  const bf16* l2b[3] = {P[1], P[2], P[5]};
  for (int i = 0; i < 3; i++) { L2.A[i] = l2a[i]; L2.B[i] = l2b[i]; L2.C[i] = Q[i]; }
  L2.nG = 3; L2.x = x; L2.xbf = xbf; L2.ubase = 2048;
  tree_level<<<dim3(192 + 256), 256, 0, stream>>>(L2);

  // 4) step 4: R = NT(Q0, Q1t) [blocks 0..63] || S = NT(xbf, Q2) [64..575]
  L3SArgs l3;
  l3.Q0 = Q[0]; l3.Q1t = Q[1]; l3.R = Rb;
  l3.xbf = xbf; l3.Q2 = Q[2]; l3.S = Sb;
  l3s_level<<<dim3(576), 256, 0, stream>>>(l3);

  // 5) out = NT(S, R), fp32 out (XCD-swizzled flat grid)
  final_gemm<<<dim3(512), 256, 0, stream>>>(Sb, Rb, out);

  (void)in_sizes; (void)n_in; (void)out_size; (void)ws_size;
}